// Round 3
// baseline (365.503 us; speedup 1.0000x reference)
//
#include <hip/hip_runtime.h>

// ---------------------------------------------------------------------------
// WindowAttention fused kernel for MI355X (gfx950) — R2
// B=1024 windows, N=64 tokens, C=256, H=8 heads, hd=32
// 256-thread blocks (4 waves, 2 heads/wave), LDS=64KB -> 2 blocks/CU.
// Q,K,P,V all register-resident via transposed projections + in-register
// butterfly layout conversion (C-layout -> MFMA A/B fragments).
// ---------------------------------------------------------------------------

typedef __attribute__((ext_vector_type(8))) __bf16 bf16x8;
typedef __attribute__((ext_vector_type(4))) float f32x4;
typedef __attribute__((ext_vector_type(4))) unsigned short u16x4;

__device__ __forceinline__ unsigned short f2bf(float f) {
  return __builtin_bit_cast(unsigned short, (__bf16)f);
}
__device__ __forceinline__ unsigned pk2(float lo, float hi) {
  return (unsigned)f2bf(lo) | ((unsigned)f2bf(hi) << 16);
}
__device__ __forceinline__ int swz256(int row, int col) {   // 256-elem (512B) rows
  return row * 256 + (col ^ ((row & 31) << 3));
}
__device__ __forceinline__ f32x4 mfma16(bf16x8 a, bf16x8 b, f32x4 c) {
  return __builtin_amdgcn_mfma_f32_16x16x32_bf16(a, b, c, 0, 0, 0);
}

// ---------------- pre-kernel 1: pack weights into fragment layout -----------
// pk[mat][w][blk][kc][lane][i] = W[64w + 16blk + (l&15)][32kc + 8(l>>4) + i]
// serves as A-frag (transposed projs) AND B-frag (normal projs) identically.
__global__ void pack_weights(const float* __restrict__ W0, const float* __restrict__ W1,
                             const float* __restrict__ W2, const float* __restrict__ W3,
                             const float* __restrict__ W4, const float* __restrict__ W5,
                             const float* __restrict__ W6, const float* __restrict__ W7,
                             unsigned short* __restrict__ pk) {
  int t = blockIdx.x * 256 + threadIdx.x;   // 65536 threads
  int mat = t >> 13;
  int w   = (t >> 11) & 3;
  int blk = (t >> 9) & 3;
  int kc  = (t >> 6) & 7;
  int l   = t & 63;
  const float* W = (mat == 0) ? W0 : (mat == 1) ? W1 : (mat == 2) ? W2 : (mat == 3) ? W3
                 : (mat == 4) ? W4 : (mat == 5) ? W5 : (mat == 6) ? W6 : W7;
  const float* src = W + (64 * w + 16 * blk + (l & 15)) * 256 + 32 * kc + 8 * (l >> 4);
  unsigned short* dst = pk + (size_t)t * 8;
#pragma unroll
  for (int i = 0; i < 8; ++i) dst[i] = f2bf(src[i]);
}

// ---------------- pre-kernel 2: bmt[wi][h][nf][mf][lane][r] -----------------
// value = mask[wi][q][k] + btab[ridx[q][k]][h], q=16nf+(l&15), k=16mf+4(l>>4)+r
__global__ void make_bmt(const float* __restrict__ mask, const float* __restrict__ btab,
                         const int* __restrict__ ridx, float* __restrict__ bmt) {
  int t = blockIdx.x * 256 + threadIdx.x;   // 2,097,152 threads
  int r  = t & 3;
  int l  = (t >> 2) & 63;
  int mf = (t >> 8) & 3;
  int nf = (t >> 10) & 3;
  int h  = (t >> 12) & 7;
  int wi = t >> 15;
  int q = 16 * nf + (l & 15);
  int k = 16 * mf + 4 * (l >> 4) + r;
  bmt[t] = mask[(wi * 64 + q) * 64 + k] + btab[ridx[q * 64 + k] * 8 + h];
}

// ---------------- butterfly: two 16x16 C-layout blocks -> one B/A-frag ------
// C0 rows 0..15, C1 rows 16..31 (same 16 cols). Output: lane (c4,r16) holds
// rows 8c4+i (i=0..7) of [C0;C1], col r16 -> bf16x8.
__device__ __forceinline__ bf16x8 butterfly(f32x4 C0, f32x4 C1, int c4, int r16) {
  unsigned a0 = pk2(C0[0], C0[1]), a1 = pk2(C0[2], C0[3]);
  unsigned b0 = pk2(C1[0], C1[1]), b1 = pk2(C1[2], C1[3]);
  int src0 = (((2 * c4) & 3) << 4) + r16;
  int src1 = (((2 * c4 + 1) & 3) << 4) + r16;
  unsigned A0 = (unsigned)__shfl((int)a0, src0);
  unsigned A1 = (unsigned)__shfl((int)a1, src0);
  unsigned A2 = (unsigned)__shfl((int)a0, src1);
  unsigned A3 = (unsigned)__shfl((int)a1, src1);
  unsigned B0 = (unsigned)__shfl((int)b0, src0);
  unsigned B1 = (unsigned)__shfl((int)b1, src0);
  unsigned B2 = (unsigned)__shfl((int)b0, src1);
  unsigned B3 = (unsigned)__shfl((int)b1, src1);
  bool hi = c4 >= 2;
  union { unsigned u[4]; bf16x8 v; } r;
  r.u[0] = hi ? B0 : A0;
  r.u[1] = hi ? B1 : A1;
  r.u[2] = hi ? B2 : A2;
  r.u[3] = hi ? B3 : A3;
  return r.v;
}

// ---------------- staging: load-early (regs) / write-late (LDS) -------------
__device__ __forceinline__ void load8(f32x4 r[8], const float* __restrict__ X,
                                      int b, int tid, int half) {
  const f32x4* src = reinterpret_cast<const f32x4*>(X + (size_t)b * 16384) + half * 2048;
#pragma unroll
  for (int it = 0; it < 8; ++it) r[it] = src[it * 256 + tid];
}
__device__ __forceinline__ void write8(unsigned short* T, const f32x4 r[8], int tid, int half) {
#pragma unroll
  for (int it = 0; it < 8; ++it) {
    int f = half * 2048 + it * 256 + tid;
    int row = f >> 6;
    int col = (f & 63) << 2;
    u16x4 p;
    p[0] = f2bf(r[it][0]); p[1] = f2bf(r[it][1]);
    p[2] = f2bf(r[it][2]); p[3] = f2bf(r[it][3]);
    *reinterpret_cast<u16x4*>(T + swz256(row, col)) = p;
  }
}

// ---------------- transposed proj: C = W @ X^T (64d x 64tok) -> frags -------
// frag[bp][nf]: lane holds M[d=8c4+i+32bp][tok=r16+16nf] (M = W X^T + bias, *scale)
__device__ __forceinline__ void projT(const unsigned short* __restrict__ T,
                                      const unsigned short* __restrict__ pw,
                                      const float* __restrict__ bias, float scale,
                                      int lane, int w, bf16x8 frag[2][4]) {
  const int r16 = lane & 15, c4 = lane >> 4;
  f32x4 z = {0.f, 0.f, 0.f, 0.f};
  f32x4 acc[4][4];
#pragma unroll
  for (int mf = 0; mf < 4; ++mf)
#pragma unroll
    for (int nf = 0; nf < 4; ++nf) acc[mf][nf] = z;
#pragma unroll
  for (int kc = 0; kc < 8; ++kc) {
    bf16x8 aw[4], bx[4];
#pragma unroll
    for (int mf = 0; mf < 4; ++mf)
      aw[mf] = *reinterpret_cast<const bf16x8*>(pw + (((mf * 8 + kc) * 64 + lane) << 3));
#pragma unroll
    for (int nf = 0; nf < 4; ++nf)
      bx[nf] = *reinterpret_cast<const bf16x8*>(T + swz256(16 * nf + r16, 32 * kc + 8 * c4));
#pragma unroll
    for (int mf = 0; mf < 4; ++mf)
#pragma unroll
      for (int nf = 0; nf < 4; ++nf) acc[mf][nf] = mfma16(aw[mf], bx[nf], acc[mf][nf]);
  }
#pragma unroll
  for (int mf = 0; mf < 4; ++mf) {
    f32x4 b4 = *reinterpret_cast<const f32x4*>(bias + 64 * w + 16 * mf + 4 * c4);
#pragma unroll
    for (int nf = 0; nf < 4; ++nf)
#pragma unroll
      for (int r = 0; r < 4; ++r) acc[mf][nf][r] = (acc[mf][nf][r] + b4[r]) * scale;
  }
#pragma unroll
  for (int bp = 0; bp < 2; ++bp)
#pragma unroll
    for (int nf = 0; nf < 4; ++nf)
      frag[bp][nf] = butterfly(acc[2 * bp][nf], acc[2 * bp + 1][nf], c4, r16);
}

// ---------------- normal proj core: acc = T(64x256) @ W^T (64 cols) ---------
__device__ __forceinline__ void projN(const unsigned short* __restrict__ T,
                                      const unsigned short* __restrict__ pw,
                                      int lane, f32x4 acc[4][4]) {
  const int r16 = lane & 15, c4 = lane >> 4;
  f32x4 z = {0.f, 0.f, 0.f, 0.f};
#pragma unroll
  for (int mf = 0; mf < 4; ++mf)
#pragma unroll
    for (int nf = 0; nf < 4; ++nf) acc[mf][nf] = z;
#pragma unroll
  for (int kc = 0; kc < 8; ++kc) {
    bf16x8 a[4], bb[4];
#pragma unroll
    for (int mf = 0; mf < 4; ++mf)
      a[mf] = *reinterpret_cast<const bf16x8*>(T + swz256(16 * mf + r16, 32 * kc + 8 * c4));
#pragma unroll
    for (int nf = 0; nf < 4; ++nf)
      bb[nf] = *reinterpret_cast<const bf16x8*>(pw + (((nf * 8 + kc) * 64 + lane) << 3));
#pragma unroll
    for (int mf = 0; mf < 4; ++mf)
#pragma unroll
      for (int nf = 0; nf < 4; ++nf) acc[mf][nf] = mfma16(a[mf], bb[nf], acc[mf][nf]);
  }
}

// V-style epilogue: add per-col bias, butterfly into PV A-frags
// Vf[nfd][bp]: lane holds V[tok=8c4+i+32bp][d=16nfd+r16]
__device__ __forceinline__ void vEpilogue(f32x4 acc[4][4], const float* __restrict__ bias,
                                          int lane, int w, bf16x8 Vf[4][2]) {
  const int r16 = lane & 15, c4 = lane >> 4;
#pragma unroll
  for (int nf = 0; nf < 4; ++nf) {
    float bb = bias[64 * w + 16 * nf + r16];
#pragma unroll
    for (int mf = 0; mf < 4; ++mf)
#pragma unroll
      for (int r = 0; r < 4; ++r) acc[mf][nf][r] += bb;
  }
#pragma unroll
  for (int bp = 0; bp < 2; ++bp)
#pragma unroll
    for (int nf = 0; nf < 4; ++nf)
      Vf[nf][bp] = butterfly(acc[2 * bp][nf], acc[2 * bp + 1][nf], c4, r16);
}

// out-proj epilogue: add col bias, store f32 [64][256] (64B segments)
__device__ __forceinline__ void storeOut(float* __restrict__ dst, f32x4 acc[4][4],
                                         const float* __restrict__ bias, int lane, int w) {
  const int r16 = lane & 15, c4 = lane >> 4;
#pragma unroll
  for (int nf = 0; nf < 4; ++nf) {
    float bb = bias[64 * w + 16 * nf + r16];
#pragma unroll
    for (int mf = 0; mf < 4; ++mf)
#pragma unroll
      for (int r = 0; r < 4; ++r)
        dst[(16 * mf + 4 * c4 + r) * 256 + 64 * w + 16 * nf + r16] = acc[mf][nf][r] + bb;
  }
}

// store O^T C-layout (one head) transposed into row-major O LDS tile
__device__ __forceinline__ void storeO(unsigned short* T, const f32x4 o[2][4],
                                       int hh, int lane, int w) {
  const int r16 = lane & 15, c4 = lane >> 4;
#pragma unroll
  for (int mfd = 0; mfd < 2; ++mfd)
#pragma unroll
    for (int nf = 0; nf < 4; ++nf)
#pragma unroll
      for (int r = 0; r < 4; ++r)
        T[swz256(16 * nf + r16, 64 * w + 32 * hh + 16 * mfd + 4 * c4 + r)] =
            f2bf(o[mfd][nf][r]);
}

// ---------------- main fused kernel: one block per window, 4 waves ----------
__global__ __launch_bounds__(256, 2) void win_attn(
    const float* __restrict__ gq, const float* __restrict__ gk, const float* __restrict__ gv,
    const float* __restrict__ gsc, const float* __restrict__ gsh,
    const unsigned short* __restrict__ pk,
    const float* __restrict__ b_q, const float* __restrict__ b_k, const float* __restrict__ b_v,
    const float* __restrict__ b_vs, const float* __restrict__ b_vh,
    const float* __restrict__ b_px, const float* __restrict__ b_ps, const float* __restrict__ b_ph,
    const float* __restrict__ bmt, float* __restrict__ out) {
  __shared__ __align__(16) unsigned short sm[32768];   // 64 KiB
  unsigned short* R0 = sm;
  unsigned short* R1 = sm + 16384;

  const int b    = blockIdx.x;
  const int tid  = threadIdx.x;
  const int lane = tid & 63;
  const int w    = tid >> 6;           // wave 0..3, heads 2w and 2w+1
  const int r16  = lane & 15, c4 = lane >> 4;
  const int wi   = b & 63;

  f32x4 rSa[8], rSb[8];
  f32x4 z = {0.f, 0.f, 0.f, 0.f};

  // prologue: stage q -> R0
  load8(rSa, gq, b, tid, 0);
  load8(rSb, gq, b, tid, 1);
  write8(R0, rSa, tid, 0);
  write8(R0, rSb, tid, 1);
  __syncthreads();                                    // bar0

  bf16x8 Qf[2][4], Kf[2][4], Pf[2][2][4];

  // P1: Q^T proj (reads R0); stage k -> R1
  load8(rSa, gk, b, tid, 0);
  load8(rSb, gk, b, tid, 1);
  projT(R0, pk + (size_t)(0 * 4 + w) * 16384, b_q, 0.17677669529663687f, lane, w, Qf);
  write8(R1, rSa, tid, 0);
  write8(R1, rSb, tid, 1);
  __syncthreads();                                    // bar1

  // P2: K^T proj (reads R1); stage v -> R0
  load8(rSa, gv, b, tid, 0);
  load8(rSb, gv, b, tid, 1);
  projT(R1, pk + (size_t)(1 * 4 + w) * 16384, b_k, 1.0f, lane, w, Kf);
  write8(R0, rSa, tid, 0);
  write8(R0, rSb, tid, 1);
  __syncthreads();                                    // bar2

  // P3: attention for both heads (registers only); stage sc -> R1
#pragma unroll
  for (int hh = 0; hh < 2; ++hh) {
    if (hh == 0) load8(rSa, gsc, b, tid, 0);
    else         load8(rSb, gsc, b, tid, 1);
    const float* bmb = bmt + ((size_t)(wi * 8 + 2 * w + hh) << 12);
#pragma unroll
    for (int nf = 0; nf < 4; ++nf) {
      f32x4 s[4];
#pragma unroll
      for (int mf = 0; mf < 4; ++mf) s[mf] = mfma16(Kf[hh][mf], Qf[hh][nf], z);
      float e[4][4];
      float mx = -1e30f;
#pragma unroll
      for (int mf = 0; mf < 4; ++mf) {
        f32x4 bm4 = *reinterpret_cast<const f32x4*>(bmb + (((nf * 4 + mf) * 64 + lane) << 2));
#pragma unroll
        for (int r = 0; r < 4; ++r) {
          float vv = s[mf][r] + bm4[r];
          e[mf][r] = vv;
          mx = fmaxf(mx, vv);
        }
      }
      mx = fmaxf(mx, __shfl_xor(mx, 16));
      mx = fmaxf(mx, __shfl_xor(mx, 32));
      float sum = 0.f;
#pragma unroll
      for (int mf = 0; mf < 4; ++mf)
#pragma unroll
        for (int r = 0; r < 4; ++r) {
          float ev = __expf(e[mf][r] - mx);
          e[mf][r] = ev;
          sum += ev;
        }
      sum += __shfl_xor(sum, 16);
      sum += __shfl_xor(sum, 32);
      float inv = 1.0f / sum;
#pragma unroll
      for (int kc = 0; kc < 2; ++kc) {
        f32x4 p0, p1;
#pragma unroll
        for (int r = 0; r < 4; ++r) {
          p0[r] = e[2 * kc][r] * inv;
          p1[r] = e[2 * kc + 1][r] * inv;
        }
        Pf[hh][kc][nf] = butterfly(p0, p1, c4, r16);
      }
    }
    if (hh == 0) write8(R1, rSa, tid, 0);
    else         write8(R1, rSb, tid, 1);
  }
  __syncthreads();                                    // bar3

  bf16x8 Vf[4][2];
  f32x4 o0[2][4], o1[2][4];

  // P4: V proj (reads R0) -> PV both heads; then O_x -> R0
  {
    f32x4 vacc[4][4];
    projN(R0, pk + (size_t)(2 * 4 + w) * 16384, lane, vacc);
    vEpilogue(vacc, b_v, lane, w, Vf);
  }
#pragma unroll
  for (int mfd = 0; mfd < 2; ++mfd)
#pragma unroll
    for (int nf = 0; nf < 4; ++nf) { o0[mfd][nf] = z; o1[mfd][nf] = z; }
#pragma unroll
  for (int kc = 0; kc < 2; ++kc)
#pragma unroll
    for (int mfd = 0; mfd < 2; ++mfd)
#pragma unroll
      for (int nf = 0; nf < 4; ++nf) {
        o0[mfd][nf] = mfma16(Vf[0 + mfd][kc], Pf[0][kc][nf], o0[mfd][nf]);
        o1[mfd][nf] = mfma16(Vf[2 + mfd][kc], Pf[1][kc][nf], o1[mfd][nf]);
      }
  __syncthreads();                                    // bar4a (R0 reads done)
  storeO(R0, o0, 0, lane, w);
  storeO(R0, o1, 1, lane, w);
  __syncthreads();                                    // bar4b

  // P5: out-proj x (reads R0); issue sh half1
  load8(rSa, gsh, b, tid, 0);
  {
    f32x4 acc[4][4];
    projN(R0, pk + (size_t)(5 * 4 + w) * 16384, lane, acc);
    storeOut(out + (size_t)b * 16384, acc, b_px, lane, w);
  }

  // P6: Vs proj (reads R1=sc) -> PV; then O_s -> R1
  {
    f32x4 vacc[4][4];
    projN(R1, pk + (size_t)(3 * 4 + w) * 16384, lane, vacc);
    vEpilogue(vacc, b_vs, lane, w, Vf);
  }
#pragma unroll
  for (int mfd = 0; mfd < 2; ++mfd)
#pragma unroll
    for (int nf = 0; nf < 4; ++nf) { o0[mfd][nf] = z; o1[mfd][nf] = z; }
#pragma unroll
  for (int kc = 0; kc < 2; ++kc)
#pragma unroll
    for (int mfd = 0; mfd < 2; ++mfd)
#pragma unroll
      for (int nf = 0; nf < 4; ++nf) {
        o0[mfd][nf] = mfma16(Vf[0 + mfd][kc], Pf[0][kc][nf], o0[mfd][nf]);
        o1[mfd][nf] = mfma16(Vf[2 + mfd][kc], Pf[1][kc][nf], o1[mfd][nf]);
      }
  __syncthreads();                                    // bar6a (R1 reads done)
  storeO(R1, o0, 0, lane, w);
  storeO(R1, o1, 1, lane, w);
  __syncthreads();                                    // bar6b

  // P7: out-proj s (reads R1); write sh -> R0 (O_x dead); issue+write sh half2
  write8(R0, rSa, tid, 0);
  load8(rSb, gsh, b, tid, 1);
  {
    f32x4 acc[4][4];
    projN(R1, pk + (size_t)(6 * 4 + w) * 16384, lane, acc);
    storeOut(out + 16777216 + (size_t)b * 16384, acc, b_ps, lane, w);
  }
  write8(R0, rSb, tid, 1);
  __syncthreads();                                    // bar7

  // P8: Vh proj (reads R0=sh) -> PV; then O_h -> R0
  {
    f32x4 vacc[4][4];
    projN(R0, pk + (size_t)(4 * 4 + w) * 16384, lane, vacc);
    vEpilogue(vacc, b_vh, lane, w, Vf);
  }
#pragma unroll
  for (int mfd = 0; mfd < 2; ++mfd)
#pragma unroll
    for (int nf = 0; nf < 4; ++nf) { o0[mfd][nf] = z; o1[mfd][nf] = z; }
#pragma unroll
  for (int kc = 0; kc < 2; ++kc)
#pragma unroll
    for (int mfd = 0; mfd < 2; ++mfd)
#pragma unroll
      for (int nf = 0; nf < 4; ++nf) {
        o0[mfd][nf] = mfma16(Vf[0 + mfd][kc], Pf[0][kc][nf], o0[mfd][nf]);
        o1[mfd][nf] = mfma16(Vf[2 + mfd][kc], Pf[1][kc][nf], o1[mfd][nf]);
      }
  __syncthreads();                                    // bar8a (R0 reads done)
  storeO(R0, o0, 0, lane, w);
  storeO(R0, o1, 1, lane, w);
  __syncthreads();                                    // bar8b

  // P9: out-proj h (reads R0)
  {
    f32x4 acc[4][4];
    projN(R0, pk + (size_t)(7 * 4 + w) * 16384, lane, acc);
    storeOut(out + 33554432 + (size_t)b * 16384, acc, b_ph, lane, w);
  }
}

// ---------------------------------------------------------------------------
extern "C" void kernel_launch(void* const* d_in, const int* in_sizes, int n_in,
                              void* d_out, int out_size, void* d_ws, size_t ws_size,
                              hipStream_t stream) {
  const float* Xq   = (const float*)d_in[0];
  const float* Xk   = (const float*)d_in[1];
  const float* Xv   = (const float*)d_in[2];
  const float* Xsc  = (const float*)d_in[3];
  const float* Xsh  = (const float*)d_in[4];
  const float* mask = (const float*)d_in[5];
  const float* Wq   = (const float*)d_in[6];  const float* bq  = (const float*)d_in[7];
  const float* Wk   = (const float*)d_in[8];  const float* bk  = (const float*)d_in[9];
  const float* Wv   = (const float*)d_in[10]; const float* bv  = (const float*)d_in[11];
  const float* Wvs  = (const float*)d_in[12]; const float* bvs = (const float*)d_in[13];
  const float* Wvh  = (const float*)d_in[14]; const float* bvh = (const float*)d_in[15];
  const float* Wpx  = (const float*)d_in[16]; const float* bpx = (const float*)d_in[17];
  const float* Wps  = (const float*)d_in[18]; const float* bps = (const float*)d_in[19];
  const float* Wph  = (const float*)d_in[20]; const float* bph = (const float*)d_in[21];
  const float* btab = (const float*)d_in[22];
  const int*   ridx = (const int*)d_in[23];

  unsigned short* pk = (unsigned short*)d_ws;                  // 8 mats x 128KB = 1 MB
  float* bmt = (float*)((char*)d_ws + (size_t)8 * 65536 * 2);  // 2M floats = 8 MB

  pack_weights<<<256, 256, 0, stream>>>(Wq, Wk, Wv, Wvs, Wvh, Wpx, Wps, Wph, pk);
  make_bmt<<<8192, 256, 0, stream>>>(mask, btab, ridx, bmt);
  win_attn<<<1024, 256, 0, stream>>>(Xq, Xk, Xv, Xsc, Xsh, pk,
                                     bq, bk, bv, bvs, bvh, bpx, bps, bph,
                                     bmt, (float*)d_out);
}

// Round 4
// 317.996 us; speedup vs baseline: 1.1494x; 1.1494x over previous
//
#include <hip/hip_runtime.h>

// ---------------------------------------------------------------------------
// WindowAttention fused kernel for MI355X (gfx950) — R3
// B=1024 windows, N=64 tokens, C=256, H=8 heads, hd=32
// 512 threads / 8 waves / 1 head per wave. Q,K,P,V register-resident
// (transposed projections + butterfly C-layout->fragment conversion).
// LDS = 64KB (XS stage + OS tile) -> 2 blocks/CU. 9 phases, 8 barriers.
// ---------------------------------------------------------------------------

typedef __attribute__((ext_vector_type(8))) __bf16 bf16x8;
typedef __attribute__((ext_vector_type(4))) float f32x4;
typedef __attribute__((ext_vector_type(4))) unsigned short u16x4;

__device__ __forceinline__ unsigned short f2bf(float f) {
  return __builtin_bit_cast(unsigned short, (__bf16)f);
}
__device__ __forceinline__ unsigned pk2(float lo, float hi) {
  return (unsigned)f2bf(lo) | ((unsigned)f2bf(hi) << 16);
}
__device__ __forceinline__ int swz256(int row, int col) {   // 256-elem (512B) rows
  return row * 256 + (col ^ ((row & 31) << 3));
}
__device__ __forceinline__ f32x4 mfma16(bf16x8 a, bf16x8 b, f32x4 c) {
  return __builtin_amdgcn_mfma_f32_16x16x32_bf16(a, b, c, 0, 0, 0);
}

// ---------------- pre-kernel 1: pack weights into fragment layout -----------
// pk[mat][w64][blk][kc][lane][i] = W[64*w64 + 16*blk + (l&15)][32*kc + 8*(l>>4) + i]
__global__ void pack_weights(const float* __restrict__ W0, const float* __restrict__ W1,
                             const float* __restrict__ W2, const float* __restrict__ W3,
                             const float* __restrict__ W4, const float* __restrict__ W5,
                             const float* __restrict__ W6, const float* __restrict__ W7,
                             unsigned short* __restrict__ pk) {
  int t = blockIdx.x * 256 + threadIdx.x;   // 65536 threads
  int mat = t >> 13;
  int w   = (t >> 11) & 3;
  int blk = (t >> 9) & 3;
  int kc  = (t >> 6) & 7;
  int l   = t & 63;
  const float* W = (mat == 0) ? W0 : (mat == 1) ? W1 : (mat == 2) ? W2 : (mat == 3) ? W3
                 : (mat == 4) ? W4 : (mat == 5) ? W5 : (mat == 6) ? W6 : W7;
  const float* src = W + (64 * w + 16 * blk + (l & 15)) * 256 + 32 * kc + 8 * (l >> 4);
  unsigned short* dst = pk + (size_t)t * 8;
#pragma unroll
  for (int i = 0; i < 8; ++i) dst[i] = f2bf(src[i]);
}

// ---------------- pre-kernel 2: bmt[wi][h][qb][t][lane][r] ------------------
// value = mask[wi][q][k] + btab[ridx[q][k]][h], q=16qb+(l&15), k=16t+4(l>>4)+r
__global__ void make_bmt(const float* __restrict__ mask, const float* __restrict__ btab,
                         const int* __restrict__ ridx, float* __restrict__ bmt) {
  int t = blockIdx.x * 256 + threadIdx.x;   // 2,097,152 threads
  int r  = t & 3;
  int l  = (t >> 2) & 63;
  int mf = (t >> 8) & 3;
  int nf = (t >> 10) & 3;
  int h  = (t >> 12) & 7;
  int wi = t >> 15;
  int q = 16 * nf + (l & 15);
  int k = 16 * mf + 4 * (l >> 4) + r;
  bmt[t] = mask[(wi * 64 + q) * 64 + k] + btab[ridx[q * 64 + k] * 8 + h];
}

// ---------------- butterfly: two 16-row C-layout blocks -> one frag ---------
// C0 rows 0..15, C1 rows 16..31 (same 16 cols). Output: lane (c4,r16) holds
// rows 8c4+i (i=0..7) of [C0;C1], col r16 -> bf16x8 (A- or B-frag layout).
__device__ __forceinline__ bf16x8 butterfly(f32x4 C0, f32x4 C1, int c4, int r16) {
  unsigned a0 = pk2(C0[0], C0[1]), a1 = pk2(C0[2], C0[3]);
  unsigned b0 = pk2(C1[0], C1[1]), b1 = pk2(C1[2], C1[3]);
  int src0 = (((2 * c4) & 3) << 4) + r16;
  int src1 = (((2 * c4 + 1) & 3) << 4) + r16;
  unsigned A0 = (unsigned)__shfl((int)a0, src0);
  unsigned A1 = (unsigned)__shfl((int)a1, src0);
  unsigned A2 = (unsigned)__shfl((int)a0, src1);
  unsigned A3 = (unsigned)__shfl((int)a1, src1);
  unsigned B0 = (unsigned)__shfl((int)b0, src0);
  unsigned B1 = (unsigned)__shfl((int)b1, src0);
  unsigned B2 = (unsigned)__shfl((int)b0, src1);
  unsigned B3 = (unsigned)__shfl((int)b1, src1);
  bool hi = c4 >= 2;
  union { unsigned u[4]; bf16x8 v; } r;
  r.u[0] = hi ? B0 : A0;
  r.u[1] = hi ? B1 : A1;
  r.u[2] = hi ? B2 : A2;
  r.u[3] = hi ? B3 : A3;
  return r.v;
}

// ---------------- staging (512 threads): load->regs, regs->LDS --------------
__device__ __forceinline__ void load_tile(f32x4 r[8], const float* __restrict__ X,
                                          int b, int tid) {
  const f32x4* src = reinterpret_cast<const f32x4*>(X + (size_t)b * 16384);
#pragma unroll
  for (int it = 0; it < 8; ++it) r[it] = src[it * 512 + tid];
}
__device__ __forceinline__ void write_tile(unsigned short* T, const f32x4 r[8], int tid) {
#pragma unroll
  for (int it = 0; it < 8; ++it) {
    int f = it * 512 + tid;
    int row = f >> 6;
    int col = (f & 63) << 2;
    u16x4 p;
    p[0] = f2bf(r[it][0]); p[1] = f2bf(r[it][1]);
    p[2] = f2bf(r[it][2]); p[3] = f2bf(r[it][3]);
    *reinterpret_cast<u16x4*>(T + swz256(row, col)) = p;
  }
}

// per-head packed-weight base: rows [32w, 32w+32) of mat
__device__ __forceinline__ const unsigned short* pwBase(const unsigned short* pk,
                                                        int mat, int w) {
  return pk + mat * 65536 + (w >> 1) * 16384 + (w & 1) * 8192;
}

// ---------------- transposed proj (one head): M = W X^T -> frags ------------
// frag[nf]: lane holds M[d=8c4+i][tok=16nf+r16]  (M incl. bias, *scale)
__device__ __forceinline__ void projT_head(const unsigned short* __restrict__ T,
                                           const unsigned short* __restrict__ pw,
                                           const float* __restrict__ bias, float scale,
                                           int lane, int w, bf16x8 frag[4]) {
  const int r16 = lane & 15, c4 = lane >> 4;
  f32x4 z = {0.f, 0.f, 0.f, 0.f};
  f32x4 acc[2][4];
#pragma unroll
  for (int j = 0; j < 2; ++j)
#pragma unroll
    for (int nf = 0; nf < 4; ++nf) acc[j][nf] = z;
#pragma unroll
  for (int kc = 0; kc < 8; ++kc) {
    bf16x8 aw[2], bx[4];
#pragma unroll
    for (int j = 0; j < 2; ++j)
      aw[j] = *reinterpret_cast<const bf16x8*>(pw + j * 4096 + kc * 512 + lane * 8);
#pragma unroll
    for (int nf = 0; nf < 4; ++nf)
      bx[nf] = *reinterpret_cast<const bf16x8*>(T + swz256(16 * nf + r16, 32 * kc + 8 * c4));
#pragma unroll
    for (int j = 0; j < 2; ++j)
#pragma unroll
      for (int nf = 0; nf < 4; ++nf) acc[j][nf] = mfma16(aw[j], bx[nf], acc[j][nf]);
  }
#pragma unroll
  for (int j = 0; j < 2; ++j) {
    f32x4 b4 = *reinterpret_cast<const f32x4*>(bias + 32 * w + 16 * j + 4 * c4);
#pragma unroll
    for (int nf = 0; nf < 4; ++nf)
#pragma unroll
      for (int r = 0; r < 4; ++r) acc[j][nf][r] = (acc[j][nf][r] + b4[r]) * scale;
  }
#pragma unroll
  for (int nf = 0; nf < 4; ++nf)
    frag[nf] = butterfly(acc[0][nf], acc[1][nf], c4, r16);
}

// ---------------- attention (one head), all-register ------------------------
// S^T = K Q^T; softmax over k (lane-local 16 + shfl 16,32); Pf = A-frags of P.
__device__ __forceinline__ void attn_head(const bf16x8 Qf[4], const bf16x8 Kf[4],
                                          const float* __restrict__ bmb,
                                          int lane, bf16x8 Pf[4][2]) {
  const int r16 = lane & 15, c4 = lane >> 4;
  f32x4 z = {0.f, 0.f, 0.f, 0.f};
#pragma unroll
  for (int qb = 0; qb < 4; ++qb) {
    f32x4 s[4];
#pragma unroll
    for (int t = 0; t < 4; ++t) s[t] = mfma16(Kf[t], Qf[qb], z);
    float mx = -1e30f;
#pragma unroll
    for (int t = 0; t < 4; ++t) {
      f32x4 bm4 = *reinterpret_cast<const f32x4*>(bmb + (((qb * 4 + t) * 64 + lane) << 2));
#pragma unroll
      for (int r = 0; r < 4; ++r) {
        s[t][r] += bm4[r];
        mx = fmaxf(mx, s[t][r]);
      }
    }
    mx = fmaxf(mx, __shfl_xor(mx, 16));
    mx = fmaxf(mx, __shfl_xor(mx, 32));
    float sum = 0.f;
#pragma unroll
    for (int t = 0; t < 4; ++t)
#pragma unroll
      for (int r = 0; r < 4; ++r) {
        s[t][r] = __expf(s[t][r] - mx);
        sum += s[t][r];
      }
    sum += __shfl_xor(sum, 16);
    sum += __shfl_xor(sum, 32);
    float inv = 1.0f / sum;
#pragma unroll
    for (int kc = 0; kc < 2; ++kc) {
      f32x4 p0, p1;
#pragma unroll
      for (int r = 0; r < 4; ++r) {
        p0[r] = s[2 * kc][r] * inv;
        p1[r] = s[2 * kc + 1][r] * inv;
      }
      Pf[qb][kc] = butterfly(p0, p1, c4, r16);
    }
  }
}

// ---------------- normal proj core: acc = T(64x256) @ W^T (32 cols) ---------
__device__ __forceinline__ void projN32(const unsigned short* __restrict__ T,
                                        const unsigned short* __restrict__ pw,
                                        int lane, f32x4 acc[4][2]) {
  const int r16 = lane & 15, c4 = lane >> 4;
  f32x4 z = {0.f, 0.f, 0.f, 0.f};
#pragma unroll
  for (int mf = 0; mf < 4; ++mf)
#pragma unroll
    for (int nf = 0; nf < 2; ++nf) acc[mf][nf] = z;
#pragma unroll
  for (int kc = 0; kc < 8; ++kc) {
    bf16x8 a[4], bb[2];
#pragma unroll
    for (int mf = 0; mf < 4; ++mf)
      a[mf] = *reinterpret_cast<const bf16x8*>(T + swz256(16 * mf + r16, 32 * kc + 8 * c4));
#pragma unroll
    for (int nf = 0; nf < 2; ++nf)
      bb[nf] = *reinterpret_cast<const bf16x8*>(pw + nf * 4096 + kc * 512 + lane * 8);
#pragma unroll
    for (int mf = 0; mf < 4; ++mf)
#pragma unroll
      for (int nf = 0; nf < 2; ++nf) acc[mf][nf] = mfma16(a[mf], bb[nf], acc[mf][nf]);
  }
}

// V epilogue: add per-col bias (d = 32w+16nf+r16), butterfly -> PV B-frags
__device__ __forceinline__ void vFrag(f32x4 acc[4][2], const float* __restrict__ bias,
                                      int lane, int w, bf16x8 Vf[2][2]) {
  const int r16 = lane & 15, c4 = lane >> 4;
#pragma unroll
  for (int nf = 0; nf < 2; ++nf) {
    float bb = bias[32 * w + 16 * nf + r16];
#pragma unroll
    for (int mf = 0; mf < 4; ++mf)
#pragma unroll
      for (int r = 0; r < 4; ++r) acc[mf][nf][r] += bb;
  }
#pragma unroll
  for (int nf = 0; nf < 2; ++nf) {
    Vf[0][nf] = butterfly(acc[0][nf], acc[1][nf], c4, r16);
    Vf[1][nf] = butterfly(acc[2][nf], acc[3][nf], c4, r16);
  }
}

// PV: O = P V for this head -> OS tile cols [32w,32w+32)
__device__ __forceinline__ void pv_store(const bf16x8 Pf[4][2], const bf16x8 Vf[2][2],
                                         unsigned short* OS, int lane, int w) {
  const int r16 = lane & 15, c4 = lane >> 4;
  f32x4 z = {0.f, 0.f, 0.f, 0.f};
  f32x4 o[4][2];
#pragma unroll
  for (int qb = 0; qb < 4; ++qb)
#pragma unroll
    for (int nf = 0; nf < 2; ++nf) o[qb][nf] = z;
#pragma unroll
  for (int kc = 0; kc < 2; ++kc)
#pragma unroll
    for (int qb = 0; qb < 4; ++qb)
#pragma unroll
      for (int nf = 0; nf < 2; ++nf)
        o[qb][nf] = mfma16(Pf[qb][kc], Vf[kc][nf], o[qb][nf]);
#pragma unroll
  for (int qb = 0; qb < 4; ++qb)
#pragma unroll
    for (int nf = 0; nf < 2; ++nf)
#pragma unroll
      for (int r = 0; r < 4; ++r)
        OS[swz256(16 * qb + 4 * c4 + r, 32 * w + 16 * nf + r16)] = f2bf(o[qb][nf][r]);
}

// out-proj: projN32 on OS, add bias, store fp32 global
__device__ __forceinline__ void outProj(const unsigned short* __restrict__ OS,
                                        const unsigned short* __restrict__ pw,
                                        const float* __restrict__ bias,
                                        float* __restrict__ dst, int lane, int w) {
  const int r16 = lane & 15, c4 = lane >> 4;
  f32x4 acc[4][2];
  projN32(OS, pw, lane, acc);
#pragma unroll
  for (int nf = 0; nf < 2; ++nf) {
    float bb = bias[32 * w + 16 * nf + r16];
#pragma unroll
    for (int mf = 0; mf < 4; ++mf)
#pragma unroll
      for (int r = 0; r < 4; ++r)
        dst[(16 * mf + 4 * c4 + r) * 256 + 32 * w + 16 * nf + r16] = acc[mf][nf][r] + bb;
  }
}

// ---------------- main fused kernel: one block per window, 8 waves ----------
__global__ __launch_bounds__(512, 4) void win_attn(
    const float* __restrict__ gq, const float* __restrict__ gk, const float* __restrict__ gv,
    const float* __restrict__ gsc, const float* __restrict__ gsh,
    const unsigned short* __restrict__ pk,
    const float* __restrict__ b_q, const float* __restrict__ b_k, const float* __restrict__ b_v,
    const float* __restrict__ b_vs, const float* __restrict__ b_vh,
    const float* __restrict__ b_px, const float* __restrict__ b_ps, const float* __restrict__ b_ph,
    const float* __restrict__ bmt, float* __restrict__ out) {
  __shared__ __align__(16) unsigned short sm[32768];   // 64 KiB
  unsigned short* XS = sm;            // input staging tile
  unsigned short* OS = sm + 16384;    // K staging (prologue), then O tile

  const int b    = blockIdx.x;
  const int tid  = threadIdx.x;
  const int lane = tid & 63;
  const int w    = tid >> 6;          // wave id == head id
  const int wi   = b & 63;

  bf16x8 Qf[4], Kf[4], Pf[4][2], Vf[2][2];
  f32x4 rS[8];

  // P0: load Xq+Xk; write XS<-q
  {
    f32x4 rQ[8];
    load_tile(rQ, gq, b, tid);
    load_tile(rS, gk, b, tid);
    write_tile(XS, rQ, tid);
  }
  __syncthreads();                                    // bar0

  // P1: projT Q (reads XS); write OS<-k; load v
  projT_head(XS, pwBase(pk, 0, w), b_q, 0.17677669529663687f, lane, w, Qf);
  write_tile(OS, rS, tid);
  load_tile(rS, gv, b, tid);
  __syncthreads();                                    // bar1

  // P2: write XS<-v; projT K (reads OS); attn -> Pf (regs only)
  write_tile(XS, rS, tid);
  projT_head(OS, pwBase(pk, 1, w), b_k, 1.0f, lane, w, Kf);
  attn_head(Qf, Kf, bmt + ((size_t)(wi * 8 + w) << 12), lane, Pf);
  __syncthreads();                                    // bar2

  // P3: projN V (reads XS) -> Vf; PV -> OS; load sc
  {
    f32x4 acc[4][2];
    projN32(XS, pwBase(pk, 2, w), lane, acc);
    vFrag(acc, b_v, lane, w, Vf);
  }
  pv_store(Pf, Vf, OS, lane, w);
  load_tile(rS, gsc, b, tid);
  __syncthreads();                                    // bar3

  // P4: out-proj x (reads OS); write XS<-sc
  outProj(OS, pwBase(pk, 5, w), b_px, out + (size_t)b * 16384, lane, w);
  write_tile(XS, rS, tid);
  __syncthreads();                                    // bar4

  // P5: projN Vs (reads XS); PV -> OS; load sh
  {
    f32x4 acc[4][2];
    projN32(XS, pwBase(pk, 3, w), lane, acc);
    vFrag(acc, b_vs, lane, w, Vf);
  }
  pv_store(Pf, Vf, OS, lane, w);
  load_tile(rS, gsh, b, tid);
  __syncthreads();                                    // bar5

  // P6: out-proj s (reads OS); write XS<-sh
  outProj(OS, pwBase(pk, 6, w), b_ps, out + 16777216 + (size_t)b * 16384, lane, w);
  write_tile(XS, rS, tid);
  __syncthreads();                                    // bar6

  // P7: projN Vh (reads XS); PV -> OS
  {
    f32x4 acc[4][2];
    projN32(XS, pwBase(pk, 4, w), lane, acc);
    vFrag(acc, b_vh, lane, w, Vf);
  }
  pv_store(Pf, Vf, OS, lane, w);
  __syncthreads();                                    // bar7

  // P8: out-proj h (reads OS)
  outProj(OS, pwBase(pk, 7, w), b_ph, out + 33554432 + (size_t)b * 16384, lane, w);
}

// ---------------------------------------------------------------------------
extern "C" void kernel_launch(void* const* d_in, const int* in_sizes, int n_in,
                              void* d_out, int out_size, void* d_ws, size_t ws_size,
                              hipStream_t stream) {
  const float* Xq   = (const float*)d_in[0];
  const float* Xk   = (const float*)d_in[1];
  const float* Xv   = (const float*)d_in[2];
  const float* Xsc  = (const float*)d_in[3];
  const float* Xsh  = (const float*)d_in[4];
  const float* mask = (const float*)d_in[5];
  const float* Wq   = (const float*)d_in[6];  const float* bq  = (const float*)d_in[7];
  const float* Wk   = (const float*)d_in[8];  const float* bk  = (const float*)d_in[9];
  const float* Wv   = (const float*)d_in[10]; const float* bv  = (const float*)d_in[11];
  const float* Wvs  = (const float*)d_in[12]; const float* bvs = (const float*)d_in[13];
  const float* Wvh  = (const float*)d_in[14]; const float* bvh = (const float*)d_in[15];
  const float* Wpx  = (const float*)d_in[16]; const float* bpx = (const float*)d_in[17];
  const float* Wps  = (const float*)d_in[18]; const float* bps = (const float*)d_in[19];
  const float* Wph  = (const float*)d_in[20]; const float* bph = (const float*)d_in[21];
  const float* btab = (const float*)d_in[22];
  const int*   ridx = (const int*)d_in[23];

  unsigned short* pk = (unsigned short*)d_ws;                  // 8 mats x 128KB = 1 MB
  float* bmt = (float*)((char*)d_ws + (size_t)8 * 65536 * 2);  // 2M floats = 8 MB

  pack_weights<<<256, 256, 0, stream>>>(Wq, Wk, Wv, Wvs, Wvh, Wpx, Wps, Wph, pk);
  make_bmt<<<8192, 256, 0, stream>>>(mask, btab, ridx, bmt);
  win_attn<<<1024, 512, 0, stream>>>(Xq, Xk, Xv, Xsc, Xsh, pk,
                                     bq, bk, bv, bvs, bvh, bpx, bps, bph,
                                     bmt, (float*)d_out);
}

// Round 5
// 215.002 us; speedup vs baseline: 1.7000x; 1.4790x over previous
//
#include <hip/hip_runtime.h>

// ---------------------------------------------------------------------------
// WindowAttention fused kernel for MI355X (gfx950) — R4
// B=1024 windows, N=64 tokens, C=256, H=8 heads, hd=32
// 512 threads / 8 waves / 1 head per wave. Q,K,P,V register-resident
// (R3's verified transposed-proj + butterfly fragment path).
// LDS = 160 KiB = five 32 KiB bf16 input tiles; dead input tiles are
// recycled as O tiles. 6 phases / 5 barriers; all HBM loads issued early
// so transfers overlap MFMA work. launch_bounds(512,2): 256-reg cap, no spill.
// ---------------------------------------------------------------------------

typedef __attribute__((ext_vector_type(8))) __bf16 bf16x8;
typedef __attribute__((ext_vector_type(4))) float f32x4;
typedef __attribute__((ext_vector_type(4))) unsigned short u16x4;

__device__ __forceinline__ unsigned short f2bf(float f) {
  return __builtin_bit_cast(unsigned short, (__bf16)f);
}
__device__ __forceinline__ unsigned pk2(float lo, float hi) {
  return (unsigned)f2bf(lo) | ((unsigned)f2bf(hi) << 16);
}
__device__ __forceinline__ int swz256(int row, int col) {   // 256-elem (512B) rows
  return row * 256 + (col ^ ((row & 31) << 3));
}
__device__ __forceinline__ f32x4 mfma16(bf16x8 a, bf16x8 b, f32x4 c) {
  return __builtin_amdgcn_mfma_f32_16x16x32_bf16(a, b, c, 0, 0, 0);
}

// ---------------- pre-kernel 1: pack weights into fragment layout -----------
// pk[mat][w64][blk][kc][lane][i] = W[64*w64 + 16*blk + (l&15)][32*kc + 8*(l>>4) + i]
__global__ void pack_weights(const float* __restrict__ W0, const float* __restrict__ W1,
                             const float* __restrict__ W2, const float* __restrict__ W3,
                             const float* __restrict__ W4, const float* __restrict__ W5,
                             const float* __restrict__ W6, const float* __restrict__ W7,
                             unsigned short* __restrict__ pk) {
  int t = blockIdx.x * 256 + threadIdx.x;   // 65536 threads
  int mat = t >> 13;
  int w   = (t >> 11) & 3;
  int blk = (t >> 9) & 3;
  int kc  = (t >> 6) & 7;
  int l   = t & 63;
  const float* W = (mat == 0) ? W0 : (mat == 1) ? W1 : (mat == 2) ? W2 : (mat == 3) ? W3
                 : (mat == 4) ? W4 : (mat == 5) ? W5 : (mat == 6) ? W6 : W7;
  const float* src = W + (64 * w + 16 * blk + (l & 15)) * 256 + 32 * kc + 8 * (l >> 4);
  unsigned short* dst = pk + (size_t)t * 8;
#pragma unroll
  for (int i = 0; i < 8; ++i) dst[i] = f2bf(src[i]);
}

// ---------------- pre-kernel 2: bmt[wi][h][qb][t][lane][r] ------------------
// value = mask[wi][q][k] + btab[ridx[q][k]][h], q=16qb+(l&15), k=16t+4(l>>4)+r
__global__ void make_bmt(const float* __restrict__ mask, const float* __restrict__ btab,
                         const int* __restrict__ ridx, float* __restrict__ bmt) {
  int t = blockIdx.x * 256 + threadIdx.x;   // 2,097,152 threads
  int r  = t & 3;
  int l  = (t >> 2) & 63;
  int mf = (t >> 8) & 3;
  int nf = (t >> 10) & 3;
  int h  = (t >> 12) & 7;
  int wi = t >> 15;
  int q = 16 * nf + (l & 15);
  int k = 16 * mf + 4 * (l >> 4) + r;
  bmt[t] = mask[(wi * 64 + q) * 64 + k] + btab[ridx[q * 64 + k] * 8 + h];
}

// ---------------- butterfly: two 16-row C-layout blocks -> one frag ---------
__device__ __forceinline__ bf16x8 butterfly(f32x4 C0, f32x4 C1, int c4, int r16) {
  unsigned a0 = pk2(C0[0], C0[1]), a1 = pk2(C0[2], C0[3]);
  unsigned b0 = pk2(C1[0], C1[1]), b1 = pk2(C1[2], C1[3]);
  int src0 = (((2 * c4) & 3) << 4) + r16;
  int src1 = (((2 * c4 + 1) & 3) << 4) + r16;
  unsigned A0 = (unsigned)__shfl((int)a0, src0);
  unsigned A1 = (unsigned)__shfl((int)a1, src0);
  unsigned A2 = (unsigned)__shfl((int)a0, src1);
  unsigned A3 = (unsigned)__shfl((int)a1, src1);
  unsigned B0 = (unsigned)__shfl((int)b0, src0);
  unsigned B1 = (unsigned)__shfl((int)b1, src0);
  unsigned B2 = (unsigned)__shfl((int)b0, src1);
  unsigned B3 = (unsigned)__shfl((int)b1, src1);
  bool hi = c4 >= 2;
  union { unsigned u[4]; bf16x8 v; } r;
  r.u[0] = hi ? B0 : A0;
  r.u[1] = hi ? B1 : A1;
  r.u[2] = hi ? B2 : A2;
  r.u[3] = hi ? B3 : A3;
  return r.v;
}

// ---------------- staging (512 threads): load->regs, regs->LDS --------------
__device__ __forceinline__ void load_tile(f32x4 r[8], const float* __restrict__ X,
                                          int b, int tid) {
  const f32x4* src = reinterpret_cast<const f32x4*>(X + (size_t)b * 16384);
#pragma unroll
  for (int it = 0; it < 8; ++it) r[it] = src[it * 512 + tid];
}
__device__ __forceinline__ void write_tile(unsigned short* T, const f32x4 r[8], int tid) {
#pragma unroll
  for (int it = 0; it < 8; ++it) {
    int f = it * 512 + tid;
    int row = f >> 6;
    int col = (f & 63) << 2;
    u16x4 p;
    p[0] = f2bf(r[it][0]); p[1] = f2bf(r[it][1]);
    p[2] = f2bf(r[it][2]); p[3] = f2bf(r[it][3]);
    *reinterpret_cast<u16x4*>(T + swz256(row, col)) = p;
  }
}

// per-head packed-weight base: rows [32w, 32w+32) of mat
__device__ __forceinline__ const unsigned short* pwBase(const unsigned short* pk,
                                                        int mat, int w) {
  return pk + mat * 65536 + (w >> 1) * 16384 + (w & 1) * 8192;
}

// ---------------- transposed proj (one head): M = W X^T -> frags ------------
// frag[nf]: lane holds M[d=8c4+i][tok=16nf+r16]  (M incl. bias, *scale)
__device__ __forceinline__ void projT_head(const unsigned short* __restrict__ T,
                                           const unsigned short* __restrict__ pw,
                                           const float* __restrict__ bias, float scale,
                                           int lane, int w, bf16x8 frag[4]) {
  const int r16 = lane & 15, c4 = lane >> 4;
  f32x4 z = {0.f, 0.f, 0.f, 0.f};
  f32x4 acc[2][4];
#pragma unroll
  for (int j = 0; j < 2; ++j)
#pragma unroll
    for (int nf = 0; nf < 4; ++nf) acc[j][nf] = z;
#pragma unroll
  for (int kc = 0; kc < 8; ++kc) {
    bf16x8 aw[2], bx[4];
#pragma unroll
    for (int j = 0; j < 2; ++j)
      aw[j] = *reinterpret_cast<const bf16x8*>(pw + j * 4096 + kc * 512 + lane * 8);
#pragma unroll
    for (int nf = 0; nf < 4; ++nf)
      bx[nf] = *reinterpret_cast<const bf16x8*>(T + swz256(16 * nf + r16, 32 * kc + 8 * c4));
#pragma unroll
    for (int j = 0; j < 2; ++j)
#pragma unroll
      for (int nf = 0; nf < 4; ++nf) acc[j][nf] = mfma16(aw[j], bx[nf], acc[j][nf]);
  }
#pragma unroll
  for (int j = 0; j < 2; ++j) {
    f32x4 b4 = *reinterpret_cast<const f32x4*>(bias + 32 * w + 16 * j + 4 * c4);
#pragma unroll
    for (int nf = 0; nf < 4; ++nf)
#pragma unroll
      for (int r = 0; r < 4; ++r) acc[j][nf][r] = (acc[j][nf][r] + b4[r]) * scale;
  }
#pragma unroll
  for (int nf = 0; nf < 4; ++nf)
    frag[nf] = butterfly(acc[0][nf], acc[1][nf], c4, r16);
}

// ---------------- attention (one head), all-register ------------------------
__device__ __forceinline__ void attn_head(const bf16x8 Qf[4], const bf16x8 Kf[4],
                                          const float* __restrict__ bmb,
                                          int lane, bf16x8 Pf[4][2]) {
  const int r16 = lane & 15, c4 = lane >> 4;
  f32x4 z = {0.f, 0.f, 0.f, 0.f};
#pragma unroll
  for (int qb = 0; qb < 4; ++qb) {
    f32x4 s[4];
#pragma unroll
    for (int t = 0; t < 4; ++t) s[t] = mfma16(Kf[t], Qf[qb], z);
    float mx = -1e30f;
#pragma unroll
    for (int t = 0; t < 4; ++t) {
      f32x4 bm4 = *reinterpret_cast<const f32x4*>(bmb + (((qb * 4 + t) * 64 + lane) << 2));
#pragma unroll
      for (int r = 0; r < 4; ++r) {
        s[t][r] += bm4[r];
        mx = fmaxf(mx, s[t][r]);
      }
    }
    mx = fmaxf(mx, __shfl_xor(mx, 16));
    mx = fmaxf(mx, __shfl_xor(mx, 32));
    float sum = 0.f;
#pragma unroll
    for (int t = 0; t < 4; ++t)
#pragma unroll
      for (int r = 0; r < 4; ++r) {
        s[t][r] = __expf(s[t][r] - mx);
        sum += s[t][r];
      }
    sum += __shfl_xor(sum, 16);
    sum += __shfl_xor(sum, 32);
    float inv = 1.0f / sum;
#pragma unroll
    for (int kc = 0; kc < 2; ++kc) {
      f32x4 p0, p1;
#pragma unroll
      for (int r = 0; r < 4; ++r) {
        p0[r] = s[2 * kc][r] * inv;
        p1[r] = s[2 * kc + 1][r] * inv;
      }
      Pf[qb][kc] = butterfly(p0, p1, c4, r16);
    }
  }
}

// ---------------- normal proj core: acc = T(64x256) @ W^T (32 cols) ---------
__device__ __forceinline__ void projN32(const unsigned short* __restrict__ T,
                                        const unsigned short* __restrict__ pw,
                                        int lane, f32x4 acc[4][2]) {
  const int r16 = lane & 15, c4 = lane >> 4;
  f32x4 z = {0.f, 0.f, 0.f, 0.f};
#pragma unroll
  for (int mf = 0; mf < 4; ++mf)
#pragma unroll
    for (int nf = 0; nf < 2; ++nf) acc[mf][nf] = z;
#pragma unroll
  for (int kc = 0; kc < 8; ++kc) {
    bf16x8 a[4], bb[2];
#pragma unroll
    for (int mf = 0; mf < 4; ++mf)
      a[mf] = *reinterpret_cast<const bf16x8*>(T + swz256(16 * mf + r16, 32 * kc + 8 * c4));
#pragma unroll
    for (int nf = 0; nf < 2; ++nf)
      bb[nf] = *reinterpret_cast<const bf16x8*>(pw + nf * 4096 + kc * 512 + lane * 8);
#pragma unroll
    for (int mf = 0; mf < 4; ++mf)
#pragma unroll
      for (int nf = 0; nf < 2; ++nf) acc[mf][nf] = mfma16(a[mf], bb[nf], acc[mf][nf]);
  }
}

// V epilogue: add per-col bias (d = 32w+16nf+r16), butterfly -> PV B-frags
__device__ __forceinline__ void vFrag(f32x4 acc[4][2], const float* __restrict__ bias,
                                      int lane, int w, bf16x8 Vf[2][2]) {
  const int r16 = lane & 15, c4 = lane >> 4;
#pragma unroll
  for (int nf = 0; nf < 2; ++nf) {
    float bb = bias[32 * w + 16 * nf + r16];
#pragma unroll
    for (int mf = 0; mf < 4; ++mf)
#pragma unroll
      for (int r = 0; r < 4; ++r) acc[mf][nf][r] += bb;
  }
#pragma unroll
  for (int nf = 0; nf < 2; ++nf) {
    Vf[0][nf] = butterfly(acc[0][nf], acc[1][nf], c4, r16);
    Vf[1][nf] = butterfly(acc[2][nf], acc[3][nf], c4, r16);
  }
}

// PV: O = P V for this head -> O tile cols [32w,32w+32)
__device__ __forceinline__ void pv_store(const bf16x8 Pf[4][2], const bf16x8 Vf[2][2],
                                         unsigned short* OS, int lane, int w) {
  const int r16 = lane & 15, c4 = lane >> 4;
  f32x4 z = {0.f, 0.f, 0.f, 0.f};
  f32x4 o[4][2];
#pragma unroll
  for (int qb = 0; qb < 4; ++qb)
#pragma unroll
    for (int nf = 0; nf < 2; ++nf) o[qb][nf] = z;
#pragma unroll
  for (int kc = 0; kc < 2; ++kc)
#pragma unroll
    for (int qb = 0; qb < 4; ++qb)
#pragma unroll
      for (int nf = 0; nf < 2; ++nf)
        o[qb][nf] = mfma16(Pf[qb][kc], Vf[kc][nf], o[qb][nf]);
#pragma unroll
  for (int qb = 0; qb < 4; ++qb)
#pragma unroll
    for (int nf = 0; nf < 2; ++nf)
#pragma unroll
      for (int r = 0; r < 4; ++r)
        OS[swz256(16 * qb + 4 * c4 + r, 32 * w + 16 * nf + r16)] = f2bf(o[qb][nf][r]);
}

// out-proj: projN32 on O tile, add bias, store fp32 global
__device__ __forceinline__ void outProj(const unsigned short* __restrict__ OS,
                                        const unsigned short* __restrict__ pw,
                                        const float* __restrict__ bias,
                                        float* __restrict__ dst, int lane, int w) {
  const int r16 = lane & 15, c4 = lane >> 4;
  f32x4 acc[4][2];
  projN32(OS, pw, lane, acc);
#pragma unroll
  for (int nf = 0; nf < 2; ++nf) {
    float bb = bias[32 * w + 16 * nf + r16];
#pragma unroll
    for (int mf = 0; mf < 4; ++mf)
#pragma unroll
      for (int r = 0; r < 4; ++r)
        dst[(16 * mf + 4 * c4 + r) * 256 + 32 * w + 16 * nf + r16] = acc[mf][nf][r] + bb;
  }
}

// ---------------- main fused kernel: one block per window, 8 waves ----------
// LDS: T0..T4 = five 32KB bf16 tiles (q,k,v,sc,sh). Recycling:
//   P2: O_x -> T0 (q dead)   P3: O_s -> T1 (k dead)   P4: O_h -> T2 (v dead)
__global__ __launch_bounds__(512, 2) void win_attn(
    const float* __restrict__ gq, const float* __restrict__ gk, const float* __restrict__ gv,
    const float* __restrict__ gsc, const float* __restrict__ gsh,
    const unsigned short* __restrict__ pk,
    const float* __restrict__ b_q, const float* __restrict__ b_k, const float* __restrict__ b_v,
    const float* __restrict__ b_vs, const float* __restrict__ b_vh,
    const float* __restrict__ b_px, const float* __restrict__ b_ps, const float* __restrict__ b_ph,
    const float* __restrict__ bmt, float* __restrict__ out) {
  __shared__ __align__(16) unsigned short sm[81920];   // 160 KiB
  unsigned short* T0 = sm;                // q   -> O_x
  unsigned short* T1 = sm + 16384;        // k   -> O_s
  unsigned short* T2 = sm + 32768;        // v   -> O_h
  unsigned short* T3 = sm + 49152;        // sc
  unsigned short* T4 = sm + 65536;        // sh

  const int b    = blockIdx.x;
  const int tid  = threadIdx.x;
  const int lane = tid & 63;
  const int w    = tid >> 6;          // wave id == head id
  const int wi   = b & 63;

  bf16x8 Qf[4], Kf[4], Pf[4][2], Vf[2][2];

  // P0: load q,k; write T0,T1
  {
    f32x4 rA[8], rB[8];
    load_tile(rA, gq, b, tid);
    load_tile(rB, gk, b, tid);
    write_tile(T0, rA, tid);
    write_tile(T1, rB, tid);
  }
  __syncthreads();                                    // bar0

  // P1: load v; Q,K projections + attention (register-only result Pf); write T2
  {
    f32x4 rA[8];
    load_tile(rA, gv, b, tid);
    projT_head(T0, pwBase(pk, 0, w), b_q, 0.17677669529663687f, lane, w, Qf);
    projT_head(T1, pwBase(pk, 1, w), b_k, 1.0f, lane, w, Kf);
    attn_head(Qf, Kf, bmt + ((size_t)(wi * 8 + w) << 12), lane, Pf);
    write_tile(T2, rA, tid);
  }
  __syncthreads();                                    // bar1

  // P2: load sc,sh; V proj + PV -> O_x into T0; write T3,T4
  {
    f32x4 rA[8], rB[8];
    load_tile(rA, gsc, b, tid);
    load_tile(rB, gsh, b, tid);
    {
      f32x4 acc[4][2];
      projN32(T2, pwBase(pk, 2, w), lane, acc);
      vFrag(acc, b_v, lane, w, Vf);
    }
    pv_store(Pf, Vf, T0, lane, w);
    write_tile(T3, rA, tid);
    write_tile(T4, rB, tid);
  }
  __syncthreads();                                    // bar2

  // P3: out-proj x (T0); Vs proj (T3) + PV -> O_s into T1
  outProj(T0, pwBase(pk, 5, w), b_px, out + (size_t)b * 16384, lane, w);
  {
    f32x4 acc[4][2];
    projN32(T3, pwBase(pk, 3, w), lane, acc);
    vFrag(acc, b_vs, lane, w, Vf);
  }
  pv_store(Pf, Vf, T1, lane, w);
  __syncthreads();                                    // bar3

  // P4: out-proj s (T1); Vh proj (T4) + PV -> O_h into T2
  outProj(T1, pwBase(pk, 6, w), b_ps, out + 16777216 + (size_t)b * 16384, lane, w);
  {
    f32x4 acc[4][2];
    projN32(T4, pwBase(pk, 4, w), lane, acc);
    vFrag(acc, b_vh, lane, w, Vf);
  }
  pv_store(Pf, Vf, T2, lane, w);
  __syncthreads();                                    // bar4

  // P5: out-proj h (T2)
  outProj(T2, pwBase(pk, 7, w), b_ph, out + 33554432 + (size_t)b * 16384, lane, w);
}

// ---------------------------------------------------------------------------
extern "C" void kernel_launch(void* const* d_in, const int* in_sizes, int n_in,
                              void* d_out, int out_size, void* d_ws, size_t ws_size,
                              hipStream_t stream) {
  const float* Xq   = (const float*)d_in[0];
  const float* Xk   = (const float*)d_in[1];
  const float* Xv   = (const float*)d_in[2];
  const float* Xsc  = (const float*)d_in[3];
  const float* Xsh  = (const float*)d_in[4];
  const float* mask = (const float*)d_in[5];
  const float* Wq   = (const float*)d_in[6];  const float* bq  = (const float*)d_in[7];
  const float* Wk   = (const float*)d_in[8];  const float* bk  = (const float*)d_in[9];
  const float* Wv   = (const float*)d_in[10]; const float* bv  = (const float*)d_in[11];
  const float* Wvs  = (const float*)d_in[12]; const float* bvs = (const float*)d_in[13];
  const float* Wvh  = (const float*)d_in[14]; const float* bvh = (const float*)d_in[15];
  const float* Wpx  = (const float*)d_in[16]; const float* bpx = (const float*)d_in[17];
  const float* Wps  = (const float*)d_in[18]; const float* bps = (const float*)d_in[19];
  const float* Wph  = (const float*)d_in[20]; const float* bph = (const float*)d_in[21];
  const float* btab = (const float*)d_in[22];
  const int*   ridx = (const int*)d_in[23];

  unsigned short* pk = (unsigned short*)d_ws;                  // 8 mats x 128KB = 1 MB
  float* bmt = (float*)((char*)d_ws + (size_t)8 * 65536 * 2);  // 2M floats = 8 MB

  pack_weights<<<256, 256, 0, stream>>>(Wq, Wk, Wv, Wvs, Wvh, Wpx, Wps, Wph, pk);
  make_bmt<<<8192, 256, 0, stream>>>(mask, btab, ridx, bmt);
  win_attn<<<1024, 512, 0, stream>>>(Xq, Xk, Xv, Xsc, Xsh, pk,
                                     bq, bk, bv, bvs, bvh, bpx, bps, bph,
                                     bmt, (float*)d_out);
}